// Round 21
// baseline (329.576 us; speedup 1.0000x reference)
//
#include <hip/hip_runtime.h>
#include <hip/hip_bf16.h>
#include <stdint.h>

#define NN 100000
#define DIN 512
#define H1C 128
#define H2C 16
#define NCLS 10
#define NB_SCAN ((NN + 255) / 256)

typedef __attribute__((ext_vector_type(8))) short s16x8;
typedef __attribute__((ext_vector_type(4))) float f32x4;
typedef __attribute__((ext_vector_type(4))) unsigned short u16x4;
typedef __attribute__((ext_vector_type(8))) unsigned short u16x8;

static __device__ __forceinline__ unsigned short f2bf(float f) {
  __hip_bfloat16 h = __float2bfloat16(f);
  return *(unsigned short*)&h;
}
static __device__ __forceinline__ float bflo(unsigned u) {
  return __uint_as_float(u << 16);
}
static __device__ __forceinline__ float bfhi(unsigned u) {
  return __uint_as_float(u & 0xffff0000u);
}

__device__ __forceinline__ int ld_src(const int* __restrict__ ei, int f, int E, int i) {
  return f ? ei[2 * (size_t)i] : ei[i];
}
__device__ __forceinline__ int ld_dst(const int* __restrict__ ei, int f, int E, int i) {
  return f ? ei[2 * ((size_t)E + (size_t)i)] : ei[(size_t)E + (size_t)i];
}

// -------- fused prolog: detect + deg=0 + W1 transpose/convert + u1 dropout mask --------
__global__ void k_pre(const int* __restrict__ ei, int* __restrict__ flag,
                      int* __restrict__ deg,
                      const float* __restrict__ W1, unsigned short* __restrict__ Wt,
                      const float* __restrict__ u1, uint4* __restrict__ m1, int n) {
  int i = blockIdx.x * 256 + threadIdx.x;
  if (blockIdx.x == 0 && threadIdx.x < 64) {
    int v = ei[2 * threadIdx.x + 1];
    unsigned long long b = __ballot(v == 0);
    if (threadIdx.x == 0) *flag = (b == ~0ull) ? 1 : 0;  // 1 => int64 layout
  }
  if (i < n) deg[i] = 0;
  if (i < H1C * DIN) {
    int nn = i >> 9, k = i & 511;
    Wt[i] = f2bf(W1[(size_t)k * H1C + nn]);
  }
  // dropout mask for u1: row's bits via ballot (lane l -> cols 2l,2l+1)
  int wave = threadIdx.x >> 6, lane = threadIdx.x & 63;
  int wrow = blockIdx.x * 4 + wave;  // 0..24999
  const float2* __restrict__ u1v = (const float2*)u1;
#pragma unroll
  for (int rr = 0; rr < 4; rr++) {
    int row = wrow + rr * 25000;
    float2 uu = u1v[(size_t)row * 64 + lane];
    unsigned long long b0 = __ballot(uu.x >= 0.5f);
    unsigned long long b1 = __ballot(uu.y >= 0.5f);
    if (lane == 0)
      m1[row] = make_uint4((unsigned)b0, (unsigned)(b0 >> 32),
                           (unsigned)b1, (unsigned)(b1 >> 32));
  }
}

// count + per-edge rank + staged {src,dst}; 4 edges/thread for atomic MLP
__global__ void k_count(const int* __restrict__ ei, const int* __restrict__ flag,
                        int E, int* __restrict__ deg, int* __restrict__ rank,
                        uint2* __restrict__ sd) {
  int f = *flag;
  int base = blockIdx.x * 1024 + threadIdx.x;
  if (base + 768 < E) {
    int i0 = base, i1 = base + 256, i2 = base + 512, i3 = base + 768;
    int s0 = ld_src(ei, f, E, i0), d0 = ld_dst(ei, f, E, i0);
    int s1 = ld_src(ei, f, E, i1), d1 = ld_dst(ei, f, E, i1);
    int s2 = ld_src(ei, f, E, i2), d2 = ld_dst(ei, f, E, i2);
    int s3 = ld_src(ei, f, E, i3), d3 = ld_dst(ei, f, E, i3);
    sd[i0] = make_uint2((unsigned)s0, (unsigned)d0);
    sd[i1] = make_uint2((unsigned)s1, (unsigned)d1);
    sd[i2] = make_uint2((unsigned)s2, (unsigned)d2);
    sd[i3] = make_uint2((unsigned)s3, (unsigned)d3);
    int r0 = atomicAdd(&deg[d0], 1);
    int r1 = atomicAdd(&deg[d1], 1);
    int r2 = atomicAdd(&deg[d2], 1);
    int r3 = atomicAdd(&deg[d3], 1);
    rank[i0] = r0; rank[i1] = r1; rank[i2] = r2; rank[i3] = r3;
  } else {
#pragma unroll
    for (int k = 0; k < 4; k++) {
      int i = base + k * 256;
      if (i < E) {
        int s = ld_src(ei, f, E, i), d = ld_dst(ei, f, E, i);
        sd[i] = make_uint2((unsigned)s, (unsigned)d);
        rank[i] = atomicAdd(&deg[d], 1);
      }
    }
  }
}

// scanA + dinv fused
__global__ void k_scanA(const int* __restrict__ deg, int* __restrict__ incl,
                        int* __restrict__ bsum, float* __restrict__ dinv, int n) {
  __shared__ int s[256];
  int i = blockIdx.x * 256 + threadIdx.x;
  int v = (i < n) ? deg[i] : 0;
  if (i < n) dinv[i] = rsqrtf((float)(v + 1));  // +1 self loop
  s[threadIdx.x] = v;
  __syncthreads();
  for (int off = 1; off < 256; off <<= 1) {
    int t = (threadIdx.x >= off) ? s[threadIdx.x - off] : 0;
    __syncthreads();
    s[threadIdx.x] += t;
    __syncthreads();
  }
  if (i < n) incl[i] = s[threadIdx.x];
  if (threadIdx.x == 255) bsum[blockIdx.x] = s[255];
}

// fused scanB+scanC: every block scans bsum in LDS, applies its own prefix
__global__ void k_scanBC(const int* __restrict__ deg, const int* __restrict__ bsum,
                         int* __restrict__ offs, int n, int E, int nb) {
  __shared__ int s[512];
  int tid = threadIdx.x;  // 512 threads
  int v = (tid < nb) ? bsum[tid] : 0;
  s[tid] = v;
  __syncthreads();
  for (int off = 1; off < 512; off <<= 1) {
    int t = (tid >= off) ? s[tid - off] : 0;
    __syncthreads();
    s[tid] += t;
    __syncthreads();
  }
  int bid = blockIdx.x;
  int pb = (bid > 0) ? s[bid - 1] : 0;  // exclusive prefix of this 256-chunk
  int i = bid * 256 + (tid & 255);
  if (tid < 256 && i < n) offs[i] = offs[i] - deg[i] + pb;  // incl -> excl + prefix
  if (bid == 0 && tid == 0) offs[n] = E;
}

// scatter: no atomics; reads staged {src,dst}; writes 4B src record
__global__ void k_scatter(const uint2* __restrict__ sd, const int* __restrict__ rank,
                          int E, const int* __restrict__ offs, int* __restrict__ csr_s) {
  int base = blockIdx.x * 1024 + threadIdx.x;
  if (base + 768 < E) {
    int i0 = base, i1 = base + 256, i2 = base + 512, i3 = base + 768;
    uint2 e0 = sd[i0], e1 = sd[i1], e2 = sd[i2], e3 = sd[i3];
    int r0 = rank[i0], r1 = rank[i1], r2 = rank[i2], r3 = rank[i3];
    int o0 = offs[e0.y], o1 = offs[e1.y], o2 = offs[e2.y], o3 = offs[e3.y];
    csr_s[o0 + r0] = (int)e0.x;
    csr_s[o1 + r1] = (int)e1.x;
    csr_s[o2 + r2] = (int)e2.x;
    csr_s[o3 + r3] = (int)e3.x;
  } else {
#pragma unroll
    for (int k = 0; k < 4; k++) {
      int i = base + k * 256;
      if (i < E) {
        uint2 e = sd[i];
        csr_s[offs[e.y] + rank[i]] = (int)e.x;
      }
    }
  }
}

// ---------------- GEMM1 (MFMA): h1' = bf16(dinv * (x @ W1))  [NN,512]x[512,128] ------
// BM=64: 1563 blocks (6/CU), LDS 27.6KB. T14 register prefetch.
#define BM 64
#define BK 64
#define LDA 72  // padded bf16 row stride (144B; ~2-way bank aliasing = free)
#define LDB 72

__global__ __launch_bounds__(256) void k_gemm1_mfma(const float* __restrict__ x,
                                                    const unsigned short* __restrict__ Wt,
                                                    const float* __restrict__ dinv,
                                                    unsigned int* __restrict__ h1u, int n) {
  __shared__ unsigned short As[BM * LDA];    // [row m][k]
  __shared__ unsigned short Bs[H1C * LDB];   // [perm col n][k]
  int tid = threadIdx.x;
  int wave = tid >> 6, lane = tid & 63;
  int wm = wave >> 1, wn = wave & 1;  // 2x2 wave grid; wave tile 32(M) x 64(N)
  int bm = blockIdx.x * BM;
  int lrow = lane & 15, lk = (lane >> 4) * 8;

  f32x4 acc[2][4];
#pragma unroll
  for (int i = 0; i < 2; i++)
#pragma unroll
    for (int j = 0; j < 4; j++) acc[i][j] = (f32x4){0.f, 0.f, 0.f, 0.f};

  float4 areg[4];
  u16x8 breg[4];

  auto loadA = [&](int k0) {
#pragma unroll
    for (int p = 0; p < 4; p++) {
      int idx = p * 256 + tid;        // 0..1023, each = 4 floats
      int r = idx >> 4, c4 = (idx & 15) * 4;
      int row = bm + r;
      areg[p] = make_float4(0.f, 0.f, 0.f, 0.f);
      if (row < n) areg[p] = *(const float4*)(x + (size_t)row * DIN + k0 + c4);
    }
  };
  auto loadB = [&](int k0) {
#pragma unroll
    for (int p = 0; p < 4; p++) {
      int idx = p * 256 + tid;        // 0..1023, each = 8 bf16 (16B)
      int r = idx >> 3, c8 = (idx & 7) * 8;
      breg[p] = *(const u16x8*)&Wt[(size_t)r * DIN + k0 + c8];
    }
  };

  loadA(0);
  loadB(0);

  for (int k0 = 0; k0 < DIN; k0 += BK) {
    // write staged regs to LDS
#pragma unroll
    for (int p = 0; p < 4; p++) {
      int idx = p * 256 + tid;
      int r = idx >> 4, c4 = (idx & 15) * 4;
      u16x4 b4;
      b4.x = f2bf(areg[p].x); b4.y = f2bf(areg[p].y);
      b4.z = f2bf(areg[p].z); b4.w = f2bf(areg[p].w);
      *(u16x4*)&As[r * LDA + c4] = b4;
      // B with row permutation psi(r) so each lane's acc nj-pairs are
      // ADJACENT output cols: psi(r)=(r&64)+(((r&1)+2*((r>>5)&1))<<4)+((r>>1)&15)
      int rb = idx >> 3, c8 = (idx & 7) * 8;
      int pr = (rb & 64) + (((rb & 1) + 2 * ((rb >> 5) & 1)) << 4) + ((rb >> 1) & 15);
      *(u16x8*)&Bs[pr * LDB + c8] = breg[p];
    }
    // prefetch next tile (in flight across the MFMA phase)
    if (k0 + BK < DIN) {
      loadA(k0 + BK);
      loadB(k0 + BK);
    }
    __syncthreads();
#pragma unroll
    for (int kk = 0; kk < 2; kk++) {
      s16x8 a[2], b[4];
#pragma unroll
      for (int mi = 0; mi < 2; mi++)
        a[mi] = *(const s16x8*)&As[(wm * 32 + mi * 16 + lrow) * LDA + kk * 32 + lk];
#pragma unroll
      for (int nj = 0; nj < 4; nj++)
        b[nj] = *(const s16x8*)&Bs[(wn * 64 + nj * 16 + lrow) * LDB + kk * 32 + lk];
#pragma unroll
      for (int mi = 0; mi < 2; mi++)
#pragma unroll
        for (int nj = 0; nj < 4; nj++)
          acc[mi][nj] = __builtin_amdgcn_mfma_f32_16x16x32_bf16(a[mi], b[nj], acc[mi][nj], 0, 0, 0);
    }
    __syncthreads();
  }
  // epilogue: scale row by dinv[row], pack 2xbf16 -> u32.
#pragma unroll
  for (int mi = 0; mi < 2; mi++) {
#pragma unroll
    for (int r = 0; r < 4; r++) {
      int row = bm + wm * 32 + mi * 16 + (lane >> 4) * 4 + r;
      if (row < n) {
        float dv = dinv[row];
        unsigned p0 = ((unsigned)f2bf(acc[mi][1][r] * dv) << 16) | (unsigned)f2bf(acc[mi][0][r] * dv);
        unsigned p1 = ((unsigned)f2bf(acc[mi][3][r] * dv) << 16) | (unsigned)f2bf(acc[mi][2][r] * dv);
        h1u[(size_t)row * 64 + wn * 32 + lrow] = p0;
        h1u[(size_t)row * 64 + wn * 32 + 16 + lrow] = p1;
      }
    }
  }
}

// ------- agg1 + bias + prelu + dropout(mask): h1' pre-scaled, weightless CSR -------
__global__ __launch_bounds__(256) void k_agg1(const unsigned int* __restrict__ h1u,
                                              const int* __restrict__ csr_s,
                                              const int* __restrict__ offs,
                                              const float* __restrict__ dinv,
                                              const float* __restrict__ b1,
                                              const float* __restrict__ aP,
                                              const uint4* __restrict__ m1,
                                              unsigned int* __restrict__ f1u, int n) {
  int wid = (blockIdx.x * 256 + threadIdx.x) >> 6;
  int lane = threadIdx.x & 63;
  if (wid >= n) return;
  int d = wid;
  int beg = offs[d], end = offs[d + 1];
  unsigned gs = h1u[(size_t)d * 64 + lane];  // self row (pre-scaled), issued early
  uint4 mv = m1[d];                          // wave-uniform 16B dropout mask
  float ax = 0.f, ay = 0.f;
  int e = beg;
  for (; e + 15 < end; e += 16) {
    int ss[16];
    unsigned gg[16];
#pragma unroll
    for (int k = 0; k < 16; k++) ss[k] = csr_s[e + k];
#pragma unroll
    for (int k = 0; k < 16; k++) gg[k] = h1u[(size_t)ss[k] * 64 + lane];
#pragma unroll
    for (int k = 0; k < 16; k++) { ax += bflo(gg[k]); ay += bfhi(gg[k]); }
  }
  for (; e + 7 < end; e += 8) {
    int ss[8];
    unsigned gg[8];
#pragma unroll
    for (int k = 0; k < 8; k++) ss[k] = csr_s[e + k];
#pragma unroll
    for (int k = 0; k < 8; k++) gg[k] = h1u[(size_t)ss[k] * 64 + lane];
#pragma unroll
    for (int k = 0; k < 8; k++) { ax += bflo(gg[k]); ay += bfhi(gg[k]); }
  }
  for (; e + 3 < end; e += 4) {
    int ss[4];
    unsigned gg[4];
#pragma unroll
    for (int k = 0; k < 4; k++) ss[k] = csr_s[e + k];
#pragma unroll
    for (int k = 0; k < 4; k++) gg[k] = h1u[(size_t)ss[k] * 64 + lane];
#pragma unroll
    for (int k = 0; k < 4; k++) { ax += bflo(gg[k]); ay += bfhi(gg[k]); }
  }
  for (; e < end; e++) {
    unsigned g = h1u[(size_t)csr_s[e] * 64 + lane];
    ax += bflo(g); ay += bfhi(g);
  }
  float di = dinv[d];
  ax = (ax + bflo(gs)) * di;
  ay = (ay + bfhi(gs)) * di;
  float2 bb = ((const float2*)b1)[lane];
  ax += bb.x; ay += bb.y;
  float al = *aP;
  ax = ax > 0.f ? ax : al * ax;
  ay = ay > 0.f ? ay : al * ay;
  unsigned long long b0 = (unsigned long long)mv.x | ((unsigned long long)mv.y << 32);
  unsigned long long b1m = (unsigned long long)mv.z | ((unsigned long long)mv.w << 32);
  ax = ((b0 >> lane) & 1ull) ? ax * 2.f : 0.f;
  ay = ((b1m >> lane) & 1ull) ? ay * 2.f : 0.f;
  unsigned pk = ((unsigned)f2bf(ay) << 16) | (unsigned)f2bf(ax);
  f1u[(size_t)d * 64 + lane] = pk;
}

// ------- GEMM2: h2'(bf16-packed [N,8]) = dinv * (feat1 @ W2) -------
__global__ __launch_bounds__(256) void k_gemm2(const unsigned int* __restrict__ f1u,
                                               const float* __restrict__ W2,
                                               const float* __restrict__ dinv,
                                               unsigned int* __restrict__ h2u, int n) {
  __shared__ float ws[H1C][H2C];        // 8KB
  __shared__ unsigned int fs[16][66];   // packed cols, padded
  int tid = threadIdx.x;
#pragma unroll
  for (int p = 0; p < 8; p++) {
    int idx = tid + p * 256;  // 0..2047
    ws[idx >> 4][idx & 15] = W2[idx];
  }
  int r0 = blockIdx.x * 16;
  {
    int r = tid >> 4, c4 = (tid & 15) * 4;
    int row = r0 + r;
    uint4 v = make_uint4(0, 0, 0, 0);
    if (row < n) v = *(const uint4*)(f1u + (size_t)row * 64 + c4);
    *(uint4*)&fs[r][c4] = v;
  }
  __syncthreads();
  int col = tid & 15, r = tid >> 4;
  float acc = 0.f;
#pragma unroll
  for (int k = 0; k < 64; k++) {
    unsigned u = fs[r][k];
    acc += bflo(u) * ws[2 * k][col] + bfhi(u) * ws[2 * k + 1][col];
  }
  int row = r0 + r;
  float dv = (row < n) ? dinv[row] : 0.f;
  acc *= dv;
  float accN = __shfl_xor(acc, 1, 64);  // neighbor col value
  if ((col & 1) == 0 && row < n) {
    unsigned pk = ((unsigned)f2bf(accN) << 16) | (unsigned)f2bf(acc);
    h2u[(size_t)row * 8 + (col >> 1)] = pk;
  }
}

// ------- agg2 + bias + prelu + dropout + FC: 8 groups x 8 lanes, h2' pre-scaled -------
__global__ __launch_bounds__(256) void k_agg2(const unsigned int* __restrict__ h2u,
                                              const int* __restrict__ csr_s,
                                              const int* __restrict__ offs,
                                              const float* __restrict__ dinv,
                                              const float* __restrict__ b2,
                                              const float* __restrict__ aP,
                                              const float* __restrict__ u2,
                                              const float* __restrict__ fcW,
                                              const float* __restrict__ fcb,
                                              float* __restrict__ out_feat2,
                                              float* __restrict__ out_logits, int n) {
  int wid = (blockIdx.x * 256 + threadIdx.x) >> 6;
  int lane = threadIdx.x & 63;
  if (wid >= n) return;
  int d = wid;
  int g = lane >> 3, j = lane & 7;  // 8 edge-groups x 8 col-pair lanes
  int beg = offs[d], end = offs[d + 1];
  unsigned gs = h2u[(size_t)d * 8 + j];  // self row (pre-scaled), issued early
  float aa = 0.f, ab = 0.f;
  int e = beg + g;
  for (; e + 8 < end; e += 16) {  // 2 gathers in flight per lane
    int s0 = csr_s[e], s1 = csr_s[e + 8];
    unsigned g0 = h2u[(size_t)s0 * 8 + j];
    unsigned g1 = h2u[(size_t)s1 * 8 + j];
    aa += bflo(g0) + bflo(g1);
    ab += bfhi(g0) + bfhi(g1);
  }
  for (; e < end; e += 8) {
    unsigned gg = h2u[(size_t)csr_s[e] * 8 + j];
    aa += bflo(gg); ab += bfhi(gg);
  }
  // reduce across the 8 groups (g = lane bits 3..5)
  aa += __shfl_xor(aa, 8, 64); aa += __shfl_xor(aa, 16, 64); aa += __shfl_xor(aa, 32, 64);
  ab += __shfl_xor(ab, 8, 64); ab += __shfl_xor(ab, 16, 64); ab += __shfl_xor(ab, 32, 64);
  float di = dinv[d];
  aa = (aa + bflo(gs)) * di;
  ab = (ab + bfhi(gs)) * di;
  aa += b2[2 * j]; ab += b2[2 * j + 1];
  float al = *aP;
  aa = aa > 0.f ? aa : al * aa;
  ab = ab > 0.f ? ab : al * ab;
  float2 uu = ((const float2*)(u2 + (size_t)d * H2C))[j];
  aa = (uu.x >= 0.5f) ? aa * 2.f : 0.f;
  ab = (uu.y >= 0.5f) ? ab * 2.f : 0.f;
  if (lane < 8) {
    float2 o; o.x = aa; o.y = ab;
    ((float2*)(out_feat2 + (size_t)d * H2C))[j] = o;
  }
  // FC: every lane holds feat2[2j],feat2[2j+1]; broadcast 8 pairs via shfl
  int c = lane & 15;
  int cc = (c < NCLS) ? c : 0;
  float lg = fcb[cc];
#pragma unroll
  for (int k = 0; k < 8; k++) {
    float va = __shfl(aa, k, 64);   // feat2[2k]
    float vb = __shfl(ab, k, 64);   // feat2[2k+1]
    lg += va * fcW[(2 * k) * NCLS + cc] + vb * fcW[(2 * k + 1) * NCLS + cc];
  }
  if (lane < NCLS) out_logits[(size_t)d * NCLS + c] = lg;
}

// ---------------- host ----------------
extern "C" void kernel_launch(void* const* d_in, const int* in_sizes, int n_in,
                              void* d_out, int out_size, void* d_ws, size_t ws_size,
                              hipStream_t stream) {
  const float* x   = (const float*)d_in[0];
  const int*   ei  = (const int*)d_in[1];
  const float* W1  = (const float*)d_in[2];
  const float* b1  = (const float*)d_in[3];
  const float* W2  = (const float*)d_in[4];
  const float* b2  = (const float*)d_in[5];
  const float* aP  = (const float*)d_in[6];
  const float* fcW = (const float*)d_in[7];
  const float* fcb = (const float*)d_in[8];
  const float* u1  = (const float*)d_in[9];
  const float* u2  = (const float*)d_in[10];
  const int E = in_sizes[1] / 2;

  float* out_feat2  = (float*)d_out;
  float* out_logits = (float*)d_out + (size_t)NN * H2C;

  char* w = (char*)d_ws;
  size_t off = 0;
  auto A = [&](size_t bytes) -> char* {
    char* p = w + off;
    off = (off + bytes + 255) & ~(size_t)255;
    return p;
  };
  int*   flag   = (int*)A(256);
  int*   deg    = (int*)A((size_t)NN * 4);
  int*   offs   = (int*)A((size_t)(NN + 1) * 4);
  float* dinv   = (float*)A((size_t)NN * 4);
  int*   bsum   = (int*)A(512 * 4);
  int*   rank   = (int*)A((size_t)E * 4);
  uint2* sd     = (uint2*)A((size_t)E * 8);
  int*   csr_s  = (int*)A((size_t)E * 4);
  unsigned int* h1u = (unsigned int*)A((size_t)NN * 64 * 4);  // bf16-packed h1' [N][128]
  unsigned int* f1u = (unsigned int*)A((size_t)NN * 64 * 4);  // bf16-packed feat1 [N][128]
  unsigned int* h2u = (unsigned int*)A((size_t)NN * 8 * 4);   // bf16-packed h2' [N][16]
  unsigned short* Wt = (unsigned short*)A((size_t)H1C * DIN * 2);
  uint4* m1     = (uint4*)A((size_t)NN * 16);                 // 128-bit dropout mask / row

  dim3 b256(256);
  int gE4 = (E + 1023) / 1024;

  k_pre<<<6250, b256, 0, stream>>>(ei, flag, deg, W1, Wt, u1, m1, NN);
  k_count<<<gE4, b256, 0, stream>>>(ei, flag, E, deg, rank, sd);
  k_scanA<<<NB_SCAN, b256, 0, stream>>>(deg, offs, bsum, dinv, NN);
  k_scanBC<<<NB_SCAN, 512, 0, stream>>>(deg, bsum, offs, NN, E, NB_SCAN);
  k_scatter<<<gE4, b256, 0, stream>>>(sd, rank, E, offs, csr_s);
  k_gemm1_mfma<<<(NN + BM - 1) / BM, b256, 0, stream>>>(x, Wt, dinv, h1u, NN);
  k_agg1<<<(NN + 3) / 4, b256, 0, stream>>>(h1u, csr_s, offs, dinv, b1, aP, m1, f1u, NN);
  k_gemm2<<<(NN + 15) / 16, b256, 0, stream>>>(f1u, W2, dinv, h2u, NN);
  k_agg2<<<(NN + 3) / 4, b256, 0, stream>>>(h2u, csr_s, offs, dinv, b2, aP, u2,
                                            fcW, fcb, out_feat2, out_logits, NN);
}

// Round 22
// 313.793 us; speedup vs baseline: 1.0503x; 1.0503x over previous
//
#include <hip/hip_runtime.h>
#include <hip/hip_bf16.h>
#include <stdint.h>

#define NN 100000
#define DIN 512
#define H1C 128
#define H2C 16
#define NCLS 10
#define NB_SCAN ((NN + 255) / 256)

typedef __attribute__((ext_vector_type(8))) short s16x8;
typedef __attribute__((ext_vector_type(4))) float f32x4;
typedef __attribute__((ext_vector_type(4))) unsigned short u16x4;
typedef __attribute__((ext_vector_type(8))) unsigned short u16x8;

static __device__ __forceinline__ unsigned short f2bf(float f) {
  __hip_bfloat16 h = __float2bfloat16(f);
  return *(unsigned short*)&h;
}
static __device__ __forceinline__ float bflo(unsigned u) {
  return __uint_as_float(u << 16);
}
static __device__ __forceinline__ float bfhi(unsigned u) {
  return __uint_as_float(u & 0xffff0000u);
}

__device__ __forceinline__ int ld_src(const int* __restrict__ ei, int f, int E, int i) {
  return f ? ei[2 * (size_t)i] : ei[i];
}
__device__ __forceinline__ int ld_dst(const int* __restrict__ ei, int f, int E, int i) {
  return f ? ei[2 * ((size_t)E + (size_t)i)] : ei[(size_t)E + (size_t)i];
}

// -------- fused prolog: detect + deg=0 + W1 transpose/convert + u1 dropout mask --------
__global__ void k_pre(const int* __restrict__ ei, int* __restrict__ flag,
                      int* __restrict__ deg,
                      const float* __restrict__ W1, unsigned short* __restrict__ Wt,
                      const float* __restrict__ u1, uint4* __restrict__ m1, int n) {
  int i = blockIdx.x * 256 + threadIdx.x;
  if (blockIdx.x == 0 && threadIdx.x < 64) {
    int v = ei[2 * threadIdx.x + 1];
    unsigned long long b = __ballot(v == 0);
    if (threadIdx.x == 0) *flag = (b == ~0ull) ? 1 : 0;  // 1 => int64 layout
  }
  if (i < n) deg[i] = 0;
  if (i < H1C * DIN) {
    int nn = i >> 9, k = i & 511;
    Wt[i] = f2bf(W1[(size_t)k * H1C + nn]);
  }
  // dropout mask for u1: row's bits via ballot (lane l -> cols 2l,2l+1)
  int wave = threadIdx.x >> 6, lane = threadIdx.x & 63;
  int wrow = blockIdx.x * 4 + wave;  // 0..24999
  const float2* __restrict__ u1v = (const float2*)u1;
#pragma unroll
  for (int rr = 0; rr < 4; rr++) {
    int row = wrow + rr * 25000;
    float2 uu = u1v[(size_t)row * 64 + lane];
    unsigned long long b0 = __ballot(uu.x >= 0.5f);
    unsigned long long b1 = __ballot(uu.y >= 0.5f);
    if (lane == 0)
      m1[row] = make_uint4((unsigned)b0, (unsigned)(b0 >> 32),
                           (unsigned)b1, (unsigned)(b1 >> 32));
  }
}

// count + per-edge rank; 4 edges/thread for atomic MLP
__global__ void k_count(const int* __restrict__ ei, const int* __restrict__ flag,
                        int E, int* __restrict__ deg, int* __restrict__ rank) {
  int f = *flag;
  int base = blockIdx.x * 1024 + threadIdx.x;
  if (base + 768 < E) {
    int d0 = ld_dst(ei, f, E, base);
    int d1 = ld_dst(ei, f, E, base + 256);
    int d2 = ld_dst(ei, f, E, base + 512);
    int d3 = ld_dst(ei, f, E, base + 768);
    int r0 = atomicAdd(&deg[d0], 1);
    int r1 = atomicAdd(&deg[d1], 1);
    int r2 = atomicAdd(&deg[d2], 1);
    int r3 = atomicAdd(&deg[d3], 1);
    rank[base] = r0;
    rank[base + 256] = r1;
    rank[base + 512] = r2;
    rank[base + 768] = r3;
  } else {
#pragma unroll
    for (int k = 0; k < 4; k++) {
      int i = base + k * 256;
      if (i < E) rank[i] = atomicAdd(&deg[ld_dst(ei, f, E, i)], 1);
    }
  }
}

// scanA + dinv fused
__global__ void k_scanA(const int* __restrict__ deg, int* __restrict__ incl,
                        int* __restrict__ bsum, float* __restrict__ dinv, int n) {
  __shared__ int s[256];
  int i = blockIdx.x * 256 + threadIdx.x;
  int v = (i < n) ? deg[i] : 0;
  if (i < n) dinv[i] = rsqrtf((float)(v + 1));  // +1 self loop
  s[threadIdx.x] = v;
  __syncthreads();
  for (int off = 1; off < 256; off <<= 1) {
    int t = (threadIdx.x >= off) ? s[threadIdx.x - off] : 0;
    __syncthreads();
    s[threadIdx.x] += t;
    __syncthreads();
  }
  if (i < n) incl[i] = s[threadIdx.x];
  if (threadIdx.x == 255) bsum[blockIdx.x] = s[255];
}

// fused scanB+scanC: every block scans bsum in LDS, applies its own prefix
__global__ void k_scanBC(const int* __restrict__ deg, const int* __restrict__ bsum,
                         int* __restrict__ offs, int n, int E, int nb) {
  __shared__ int s[512];
  int tid = threadIdx.x;  // 512 threads
  int v = (tid < nb) ? bsum[tid] : 0;
  s[tid] = v;
  __syncthreads();
  for (int off = 1; off < 512; off <<= 1) {
    int t = (tid >= off) ? s[tid - off] : 0;
    __syncthreads();
    s[tid] += t;
    __syncthreads();
  }
  int bid = blockIdx.x;
  int pb = (bid > 0) ? s[bid - 1] : 0;  // exclusive prefix of this 256-chunk
  int i = bid * 256 + (tid & 255);
  if (tid < 256 && i < n) offs[i] = offs[i] - deg[i] + pb;  // incl -> excl + prefix
  if (bid == 0 && tid == 0) offs[n] = E;
}

// scatter: no atomics; 4 edges/thread, 4 random writes in flight
__global__ void k_scatter(const int* __restrict__ ei, const int* __restrict__ flag, int E,
                          const int* __restrict__ offs, const int* __restrict__ rank,
                          const float* __restrict__ dinv, uint2* __restrict__ csr_sw) {
  int f = *flag;
  int base = blockIdx.x * 1024 + threadIdx.x;
  if (base + 768 < E) {
    int i0 = base, i1 = base + 256, i2 = base + 512, i3 = base + 768;
    int s0 = ld_src(ei, f, E, i0), d0 = ld_dst(ei, f, E, i0);
    int s1 = ld_src(ei, f, E, i1), d1 = ld_dst(ei, f, E, i1);
    int s2 = ld_src(ei, f, E, i2), d2 = ld_dst(ei, f, E, i2);
    int s3 = ld_src(ei, f, E, i3), d3 = ld_dst(ei, f, E, i3);
    int r0 = rank[i0], r1 = rank[i1], r2 = rank[i2], r3 = rank[i3];
    int o0 = offs[d0], o1 = offs[d1], o2 = offs[d2], o3 = offs[d3];
    float w0 = dinv[s0], w1 = dinv[s1], w2 = dinv[s2], w3 = dinv[s3];
    csr_sw[o0 + r0] = make_uint2((unsigned)s0, __float_as_uint(w0));
    csr_sw[o1 + r1] = make_uint2((unsigned)s1, __float_as_uint(w1));
    csr_sw[o2 + r2] = make_uint2((unsigned)s2, __float_as_uint(w2));
    csr_sw[o3 + r3] = make_uint2((unsigned)s3, __float_as_uint(w3));
  } else {
#pragma unroll
    for (int k = 0; k < 4; k++) {
      int i = base + k * 256;
      if (i < E) {
        int s = ld_src(ei, f, E, i), d = ld_dst(ei, f, E, i);
        int pos = offs[d] + rank[i];
        csr_sw[pos] = make_uint2((unsigned)s, __float_as_uint(dinv[s]));
      }
    }
  }
}

// ---------------- GEMM1 (MFMA): h1 = bf16(x @ W1)  [NN,512]x[512,128] ----------------
// BM=64: 1563 blocks (6/CU), LDS 27.6KB. T14 register prefetch.
#define BM 64
#define BK 64
#define LDA 72  // padded bf16 row stride (144B; ~2-way bank aliasing = free)
#define LDB 72

__global__ __launch_bounds__(256) void k_gemm1_mfma(const float* __restrict__ x,
                                                    const unsigned short* __restrict__ Wt,
                                                    unsigned int* __restrict__ h1u, int n) {
  __shared__ unsigned short As[BM * LDA];    // [row m][k]
  __shared__ unsigned short Bs[H1C * LDB];   // [perm col n][k]
  int tid = threadIdx.x;
  int wave = tid >> 6, lane = tid & 63;
  int wm = wave >> 1, wn = wave & 1;  // 2x2 wave grid; wave tile 32(M) x 64(N)
  int bm = blockIdx.x * BM;
  int lrow = lane & 15, lk = (lane >> 4) * 8;

  f32x4 acc[2][4];
#pragma unroll
  for (int i = 0; i < 2; i++)
#pragma unroll
    for (int j = 0; j < 4; j++) acc[i][j] = (f32x4){0.f, 0.f, 0.f, 0.f};

  float4 areg[4];
  u16x8 breg[4];

  auto loadA = [&](int k0) {
#pragma unroll
    for (int p = 0; p < 4; p++) {
      int idx = p * 256 + tid;        // 0..1023, each = 4 floats
      int r = idx >> 4, c4 = (idx & 15) * 4;
      int row = bm + r;
      areg[p] = make_float4(0.f, 0.f, 0.f, 0.f);
      if (row < n) areg[p] = *(const float4*)(x + (size_t)row * DIN + k0 + c4);
    }
  };
  auto loadB = [&](int k0) {
#pragma unroll
    for (int p = 0; p < 4; p++) {
      int idx = p * 256 + tid;        // 0..1023, each = 8 bf16 (16B)
      int r = idx >> 3, c8 = (idx & 7) * 8;
      breg[p] = *(const u16x8*)&Wt[(size_t)r * DIN + k0 + c8];
    }
  };

  loadA(0);
  loadB(0);

  for (int k0 = 0; k0 < DIN; k0 += BK) {
    // write staged regs to LDS
#pragma unroll
    for (int p = 0; p < 4; p++) {
      int idx = p * 256 + tid;
      int r = idx >> 4, c4 = (idx & 15) * 4;
      u16x4 b4;
      b4.x = f2bf(areg[p].x); b4.y = f2bf(areg[p].y);
      b4.z = f2bf(areg[p].z); b4.w = f2bf(areg[p].w);
      *(u16x4*)&As[r * LDA + c4] = b4;
      // B with row permutation psi(r) so each lane's acc nj-pairs are
      // ADJACENT output cols: psi(r)=(r&64)+(((r&1)+2*((r>>5)&1))<<4)+((r>>1)&15)
      int rb = idx >> 3, c8 = (idx & 7) * 8;
      int pr = (rb & 64) + (((rb & 1) + 2 * ((rb >> 5) & 1)) << 4) + ((rb >> 1) & 15);
      *(u16x8*)&Bs[pr * LDB + c8] = breg[p];
    }
    // prefetch next tile (in flight across the MFMA phase)
    if (k0 + BK < DIN) {
      loadA(k0 + BK);
      loadB(k0 + BK);
    }
    __syncthreads();
#pragma unroll
    for (int kk = 0; kk < 2; kk++) {
      s16x8 a[2], b[4];
#pragma unroll
      for (int mi = 0; mi < 2; mi++)
        a[mi] = *(const s16x8*)&As[(wm * 32 + mi * 16 + lrow) * LDA + kk * 32 + lk];
#pragma unroll
      for (int nj = 0; nj < 4; nj++)
        b[nj] = *(const s16x8*)&Bs[(wn * 64 + nj * 16 + lrow) * LDB + kk * 32 + lk];
#pragma unroll
      for (int mi = 0; mi < 2; mi++)
#pragma unroll
        for (int nj = 0; nj < 4; nj++)
          acc[mi][nj] = __builtin_amdgcn_mfma_f32_16x16x32_bf16(a[mi], b[nj], acc[mi][nj], 0, 0, 0);
    }
    __syncthreads();
  }
  // epilogue: lane holds output col pairs (2*lrow, 2*lrow+1) = (nj0,nj1),
  // (2*lrow+32, +33) = (nj2,nj3) within wn*64 half. Pack 2xbf16 -> u32.
#pragma unroll
  for (int mi = 0; mi < 2; mi++) {
#pragma unroll
    for (int r = 0; r < 4; r++) {
      int row = bm + wm * 32 + mi * 16 + (lane >> 4) * 4 + r;
      if (row < n) {
        unsigned p0 = ((unsigned)f2bf(acc[mi][1][r]) << 16) | (unsigned)f2bf(acc[mi][0][r]);
        unsigned p1 = ((unsigned)f2bf(acc[mi][3][r]) << 16) | (unsigned)f2bf(acc[mi][2][r]);
        h1u[(size_t)row * 64 + wn * 32 + lrow] = p0;
        h1u[(size_t)row * 64 + wn * 32 + 16 + lrow] = p1;
      }
    }
  }
}

// ------- agg1 + bias + prelu + dropout(mask): feat1 (bf16-packed), 16-deep MLP -------
__global__ __launch_bounds__(256) void k_agg1(const unsigned int* __restrict__ h1u,
                                              const uint2* __restrict__ csr_sw,
                                              const int* __restrict__ offs,
                                              const float* __restrict__ dinv,
                                              const float* __restrict__ b1,
                                              const float* __restrict__ aP,
                                              const uint4* __restrict__ m1,
                                              unsigned int* __restrict__ f1u, int n) {
  int wid = (blockIdx.x * 256 + threadIdx.x) >> 6;
  int lane = threadIdx.x & 63;
  if (wid >= n) return;
  int d = wid;
  int beg = offs[d], end = offs[d + 1];
  unsigned gs = h1u[(size_t)d * 64 + lane];  // self row, issued early
  uint4 mv = m1[d];                          // wave-uniform 16B dropout mask
  float ax = 0.f, ay = 0.f;
  int e = beg;
  for (; e + 15 < end; e += 16) {
    uint2 rr[16];
    unsigned gg[16];
#pragma unroll
    for (int k = 0; k < 16; k++) rr[k] = csr_sw[e + k];
#pragma unroll
    for (int k = 0; k < 16; k++) gg[k] = h1u[(size_t)rr[k].x * 64 + lane];
#pragma unroll
    for (int k = 0; k < 16; k++) {
      float w = __uint_as_float(rr[k].y);
      ax += w * bflo(gg[k]); ay += w * bfhi(gg[k]);
    }
  }
  for (; e + 7 < end; e += 8) {
    uint2 rr[8];
    unsigned gg[8];
#pragma unroll
    for (int k = 0; k < 8; k++) rr[k] = csr_sw[e + k];
#pragma unroll
    for (int k = 0; k < 8; k++) gg[k] = h1u[(size_t)rr[k].x * 64 + lane];
#pragma unroll
    for (int k = 0; k < 8; k++) {
      float w = __uint_as_float(rr[k].y);
      ax += w * bflo(gg[k]); ay += w * bfhi(gg[k]);
    }
  }
  for (; e + 3 < end; e += 4) {
    uint2 rr[4];
    unsigned gg[4];
#pragma unroll
    for (int k = 0; k < 4; k++) rr[k] = csr_sw[e + k];
#pragma unroll
    for (int k = 0; k < 4; k++) gg[k] = h1u[(size_t)rr[k].x * 64 + lane];
#pragma unroll
    for (int k = 0; k < 4; k++) {
      float w = __uint_as_float(rr[k].y);
      ax += w * bflo(gg[k]); ay += w * bfhi(gg[k]);
    }
  }
  for (; e < end; e++) {
    uint2 rr = csr_sw[e];
    float w = __uint_as_float(rr.y);
    unsigned g = h1u[(size_t)rr.x * 64 + lane];
    ax += w * bflo(g); ay += w * bfhi(g);
  }
  float di = dinv[d];
  ax = (ax + di * bflo(gs)) * di;
  ay = (ay + di * bfhi(gs)) * di;
  float2 bb = ((const float2*)b1)[lane];
  ax += bb.x; ay += bb.y;
  float al = *aP;
  ax = ax > 0.f ? ax : al * ax;
  ay = ay > 0.f ? ay : al * ay;
  unsigned long long b0 = (unsigned long long)mv.x | ((unsigned long long)mv.y << 32);
  unsigned long long b1m = (unsigned long long)mv.z | ((unsigned long long)mv.w << 32);
  ax = ((b0 >> lane) & 1ull) ? ax * 2.f : 0.f;
  ay = ((b1m >> lane) & 1ull) ? ay * 2.f : 0.f;
  unsigned pk = ((unsigned)f2bf(ay) << 16) | (unsigned)f2bf(ax);
  f1u[(size_t)d * 64 + lane] = pk;
}

// ---------------- GEMM2: h2(bf16-packed [N,8]) = feat1 @ W2 ----------------
__global__ __launch_bounds__(256) void k_gemm2(const unsigned int* __restrict__ f1u,
                                               const float* __restrict__ W2,
                                               unsigned int* __restrict__ h2u, int n) {
  __shared__ float ws[H1C][H2C];        // 8KB
  __shared__ unsigned int fs[16][66];   // packed cols, padded
  int tid = threadIdx.x;
#pragma unroll
  for (int p = 0; p < 8; p++) {
    int idx = tid + p * 256;  // 0..2047
    ws[idx >> 4][idx & 15] = W2[idx];
  }
  int r0 = blockIdx.x * 16;
  {
    int r = tid >> 4, c4 = (tid & 15) * 4;
    int row = r0 + r;
    uint4 v = make_uint4(0, 0, 0, 0);
    if (row < n) v = *(const uint4*)(f1u + (size_t)row * 64 + c4);
    *(uint4*)&fs[r][c4] = v;
  }
  __syncthreads();
  int col = tid & 15, r = tid >> 4;
  float acc = 0.f;
#pragma unroll
  for (int k = 0; k < 64; k++) {
    unsigned u = fs[r][k];
    acc += bflo(u) * ws[2 * k][col] + bfhi(u) * ws[2 * k + 1][col];
  }
  int row = r0 + r;
  float accN = __shfl_xor(acc, 1, 64);  // neighbor col value
  if ((col & 1) == 0 && row < n) {
    unsigned pk = ((unsigned)f2bf(accN) << 16) | (unsigned)f2bf(acc);
    h2u[(size_t)row * 8 + (col >> 1)] = pk;
  }
}

// ------- agg2 + bias + prelu + dropout + FC: 8 groups x 8 lanes, bf16 h2 -------
__global__ __launch_bounds__(256) void k_agg2(const unsigned int* __restrict__ h2u,
                                              const uint2* __restrict__ csr_sw,
                                              const int* __restrict__ offs,
                                              const float* __restrict__ dinv,
                                              const float* __restrict__ b2,
                                              const float* __restrict__ aP,
                                              const float* __restrict__ u2,
                                              const float* __restrict__ fcW,
                                              const float* __restrict__ fcb,
                                              float* __restrict__ out_feat2,
                                              float* __restrict__ out_logits, int n) {
  int wid = (blockIdx.x * 256 + threadIdx.x) >> 6;
  int lane = threadIdx.x & 63;
  if (wid >= n) return;
  int d = wid;
  int g = lane >> 3, j = lane & 7;  // 8 edge-groups x 8 col-pair lanes
  int beg = offs[d], end = offs[d + 1];
  unsigned gs = h2u[(size_t)d * 8 + j];  // self row, issued early
  float aa = 0.f, ab = 0.f;
  int e = beg + g;
  for (; e + 8 < end; e += 16) {  // 2 gathers in flight per lane
    uint2 r0 = csr_sw[e], r1 = csr_sw[e + 8];
    unsigned g0 = h2u[(size_t)r0.x * 8 + j];
    unsigned g1 = h2u[(size_t)r1.x * 8 + j];
    float w0 = __uint_as_float(r0.y), w1 = __uint_as_float(r1.y);
    aa += w0 * bflo(g0) + w1 * bflo(g1);
    ab += w0 * bfhi(g0) + w1 * bfhi(g1);
  }
  for (; e < end; e += 8) {
    uint2 rr = csr_sw[e];
    unsigned gg = h2u[(size_t)rr.x * 8 + j];
    float w = __uint_as_float(rr.y);
    aa += w * bflo(gg); ab += w * bfhi(gg);
  }
  // reduce across the 8 groups (g = lane bits 3..5)
  aa += __shfl_xor(aa, 8, 64); aa += __shfl_xor(aa, 16, 64); aa += __shfl_xor(aa, 32, 64);
  ab += __shfl_xor(ab, 8, 64); ab += __shfl_xor(ab, 16, 64); ab += __shfl_xor(ab, 32, 64);
  float di = dinv[d];
  aa = (aa + di * bflo(gs)) * di;
  ab = (ab + di * bfhi(gs)) * di;
  aa += b2[2 * j]; ab += b2[2 * j + 1];
  float al = *aP;
  aa = aa > 0.f ? aa : al * aa;
  ab = ab > 0.f ? ab : al * ab;
  float2 uu = ((const float2*)(u2 + (size_t)d * H2C))[j];
  aa = (uu.x >= 0.5f) ? aa * 2.f : 0.f;
  ab = (uu.y >= 0.5f) ? ab * 2.f : 0.f;
  if (lane < 8) {
    float2 o; o.x = aa; o.y = ab;
    ((float2*)(out_feat2 + (size_t)d * H2C))[j] = o;
  }
  // FC: every lane holds feat2[2j],feat2[2j+1]; broadcast 8 pairs via shfl
  int c = lane & 15;
  int cc = (c < NCLS) ? c : 0;
  float lg = fcb[cc];
#pragma unroll
  for (int k = 0; k < 8; k++) {
    float va = __shfl(aa, k, 64);   // feat2[2k]
    float vb = __shfl(ab, k, 64);   // feat2[2k+1]
    lg += va * fcW[(2 * k) * NCLS + cc] + vb * fcW[(2 * k + 1) * NCLS + cc];
  }
  if (lane < NCLS) out_logits[(size_t)d * NCLS + c] = lg;
}

// ---------------- host ----------------
extern "C" void kernel_launch(void* const* d_in, const int* in_sizes, int n_in,
                              void* d_out, int out_size, void* d_ws, size_t ws_size,
                              hipStream_t stream) {
  const float* x   = (const float*)d_in[0];
  const int*   ei  = (const int*)d_in[1];
  const float* W1  = (const float*)d_in[2];
  const float* b1  = (const float*)d_in[3];
  const float* W2  = (const float*)d_in[4];
  const float* b2  = (const float*)d_in[5];
  const float* aP  = (const float*)d_in[6];
  const float* fcW = (const float*)d_in[7];
  const float* fcb = (const float*)d_in[8];
  const float* u1  = (const float*)d_in[9];
  const float* u2  = (const float*)d_in[10];
  const int E = in_sizes[1] / 2;

  float* out_feat2  = (float*)d_out;
  float* out_logits = (float*)d_out + (size_t)NN * H2C;

  char* w = (char*)d_ws;
  size_t off = 0;
  auto A = [&](size_t bytes) -> char* {
    char* p = w + off;
    off = (off + bytes + 255) & ~(size_t)255;
    return p;
  };
  int*   flag   = (int*)A(256);
  int*   deg    = (int*)A((size_t)NN * 4);
  int*   offs   = (int*)A((size_t)(NN + 1) * 4);
  float* dinv   = (float*)A((size_t)NN * 4);
  int*   bsum   = (int*)A(512 * 4);
  int*   rank   = (int*)A((size_t)E * 4);
  uint2* csr_sw = (uint2*)A((size_t)E * 8);
  unsigned int* h1u = (unsigned int*)A((size_t)NN * 64 * 4);  // bf16-packed [N][128]
  unsigned int* f1u = (unsigned int*)A((size_t)NN * 64 * 4);  // bf16-packed [N][128]
  unsigned int* h2u = (unsigned int*)A((size_t)NN * 8 * 4);   // bf16-packed [N][16]
  unsigned short* Wt = (unsigned short*)A((size_t)H1C * DIN * 2);
  uint4* m1     = (uint4*)A((size_t)NN * 16);                 // 128-bit dropout mask / row

  dim3 b256(256);
  int gE4 = (E + 1023) / 1024;

  k_pre<<<6250, b256, 0, stream>>>(ei, flag, deg, W1, Wt, u1, m1, NN);
  k_count<<<gE4, b256, 0, stream>>>(ei, flag, E, deg, rank);
  k_scanA<<<NB_SCAN, b256, 0, stream>>>(deg, offs, bsum, dinv, NN);
  k_scanBC<<<NB_SCAN, 512, 0, stream>>>(deg, bsum, offs, NN, E, NB_SCAN);
  k_scatter<<<gE4, b256, 0, stream>>>(ei, flag, E, offs, rank, dinv, csr_sw);
  k_gemm1_mfma<<<(NN + BM - 1) / BM, b256, 0, stream>>>(x, Wt, h1u, NN);
  k_agg1<<<(NN + 3) / 4, b256, 0, stream>>>(h1u, csr_sw, offs, dinv, b1, aP, m1, f1u, NN);
  k_gemm2<<<(NN + 15) / 16, b256, 0, stream>>>(f1u, W2, h2u, NN);
  k_agg2<<<(NN + 3) / 4, b256, 0, stream>>>(h2u, csr_sw, offs, dinv, b2, aP, u2,
                                            fcW, fcb, out_feat2, out_logits, NN);
}